// Round 5
// baseline (592.000 us; speedup 1.0000x reference)
//
#include <hip/hip_runtime.h>
#include <cstdint>
#include <cstddef>

// ---------------------------------------------------------------------------
// Pipeline (bf16 MFMA, fp32 accumulate):
//   ln_q:   qn = LN(x_q)*qlnw+qlnb (bf16), also copy x_q -> out0 (fp32)
//   ln_kv:  kn = LN(x_kv)*klnw+klnb, vn = LN(x_kv)*vlnw+vlnb (bf16)
//   prep:   qwb=bf16(q_w); {kwb=bf16(k_w), qkb=q_b@k_w^T} fused; vwT=bf16(v_w^T)
//   GEMM-W:  Wt = kwb @ qwb^T        [1024,4096]  split-K x2 -> reduce (bf16)
//   GEMM-QK: part_z = qn @ Wt^T      [4608,1024]  split-K x2 (f32 partials)
//   att_fused: qk=sum part+qkb; logits=(qk.kn_s)/64; softmax(4); wkv=sum att*vn
//   GEMM-F:  out1 = wkv @ vwT^T + v_b [4608,4096]
// R5: GEMM K-loop restructured to T3 minimum-2-phase (double-buffered LDS,
// prefetch issued BEFORE compute, single vmcnt(0)+barrier per tile) + T5
// setprio around MFMA. Swizzle (T2-style XOR on 16B groups, pre-swizzled
// global source per rule #21) unchanged from R4 (validated).
// ---------------------------------------------------------------------------

typedef __attribute__((ext_vector_type(8))) short short8;
typedef __attribute__((ext_vector_type(4))) float f32x4;

#define DEV __device__ __forceinline__

DEV unsigned short f2bf(float f) {            // f32 -> bf16 RNE
  union { float f; unsigned u; } x; x.f = f;
  unsigned r = x.u + 0x7fffu + ((x.u >> 16) & 1u);
  return (unsigned short)(r >> 16);
}
DEV float bf2f(unsigned short u) {            // bf16 -> f32 exact
  union { unsigned u; float f; } x; x.u = ((unsigned)u) << 16;
  return x.f;
}

DEV void gload16(const void* g, void* l) {    // async global->LDS, 16B/lane
  __builtin_amdgcn_global_load_lds(
      (const __attribute__((address_space(1))) unsigned int*)g,
      (__attribute__((address_space(3))) unsigned int*)l, 16, 0, 0);
}

// ---------------------------------------------------------------------------
// NT GEMM, BK=64, double-buffered T2-swizzled LDS, 2-phase prefetch pipeline.
// A[M,Kfull] bf16 rm, B[N,Kfull] bf16 rm (K-contig). Split-K via blockIdx.z
// (Kchunk each); PARTIAL writes f32 partial at Cv + z*M*N. 128x128 tile,
// 4 waves 2x2, 4x4 of 16x16x32 MFMA, 2 k-steps per LDS tile.
// M,N % 128 == 0, Kchunk % 64 == 0. LDS 64 KiB -> 2 blocks/CU.
// LDS layout [row][8 groups of 16B]; group g holds global group g^(row&7)
// (involution; staged via pre-swizzled SOURCE addr, read with same XOR).
// Loop invariants: buf staged in iter t is read in iter t+1 (RAW closed by
// end-of-t vmcnt(0)+barrier); buf staged in t+1 was last read in t-1 (WAR
// closed by end-of-t barrier).
// ---------------------------------------------------------------------------
template <bool PARTIAL, bool OUT_BF16, bool HAS_BIAS>
__global__ __launch_bounds__(256, 2) void gemm_nt(
    const unsigned short* __restrict__ A, const unsigned short* __restrict__ Bm,
    void* __restrict__ Cv, const float* __restrict__ bias, int M, int N,
    int Kfull, int Kchunk) {
  __shared__ __align__(16) unsigned short lds_a[2][128 * 64];
  __shared__ __align__(16) unsigned short lds_b[2][128 * 64];
  const int t = threadIdx.x;
  const int l = t & 63;
  const int w = t >> 6;

  int bx = blockIdx.x, by = blockIdx.y;
  {  // XCD swizzle (T1): xy-plane size is a multiple of 8 at every call site
    const int nbx = gridDim.x, nby = gridDim.y;
    const int nwg = nbx * nby;
    int flat = by * nbx + bx;
    flat = (flat & 7) * (nwg >> 3) + (flat >> 3);
    bx = flat % nbx;
    by = flat / nbx;
  }
  const long brow = (long)bx * 128;
  const long bcol = (long)by * 128;
  const int z = blockIdx.z;
  const int k0 = z * Kchunk;

  // staging: 1024 16B-slots per matrix; thread owns slots t+256j (j=0..3).
  // slot s: row = s>>3, g = s&7. source group = g ^ (row&7) (const per thread)
  const int srow0 = t >> 3;
  const int gsrc = (t & 7) ^ ((t >> 3) & 7);
  const unsigned short* aS[4];
  const unsigned short* bS[4];
#pragma unroll
  for (int j = 0; j < 4; ++j) {
    const long row = srow0 + 32 * j;
    aS[j] = A + (brow + row) * (long)Kfull + k0 + gsrc * 8;
    bS[j] = Bm + (bcol + row) * (long)Kfull + k0 + gsrc * 8;
  }
  const int dOff = t * 8;  // lds elem offset of slot j=0 (others +2048*j)

  const int wr = w >> 1, wc = w & 1;
  const int fr = l & 15;              // A-row / B-col within fragment
  const int xr = fr & 7;              // row-part of the group XOR
  const int gq0 = l >> 4;             // k-group within 32-k step (0..3)

  f32x4 acc[4][4] = {};

  // prologue: stage tile 0 into buf 0, drain, barrier
#pragma unroll
  for (int j = 0; j < 4; ++j) {
    gload16(aS[j], &lds_a[0][dOff + 2048 * j]);
    gload16(bS[j], &lds_b[0][dOff + 2048 * j]);
  }
  asm volatile("s_waitcnt vmcnt(0)" ::: "memory");
  __syncthreads();

  int cur = 0;
  for (int kt = 0; kt < Kchunk; kt += 64) {
    const int nxt = cur ^ 1;
    if (kt + 64 < Kchunk) {           // issue next tile's loads (overlap)
#pragma unroll
      for (int j = 0; j < 4; ++j) {
        gload16(aS[j] + kt + 64, &lds_a[nxt][dOff + 2048 * j]);
        gload16(bS[j] + kt + 64, &lds_b[nxt][dOff + 2048 * j]);
      }
    }
#pragma unroll
    for (int ks = 0; ks < 2; ++ks) {
      const int gx = ((ks * 4 + gq0) ^ xr) * 8;   // swizzled 16B group offset
      short8 af[4], bfr[4];
#pragma unroll
      for (int mi = 0; mi < 4; ++mi)
        af[mi] = *(const short8*)&lds_a[cur][(wr * 64 + mi * 16 + fr) * 64 + gx];
#pragma unroll
      for (int ni = 0; ni < 4; ++ni)
        bfr[ni] = *(const short8*)&lds_b[cur][(wc * 64 + ni * 16 + fr) * 64 + gx];
      __builtin_amdgcn_s_setprio(1);
#pragma unroll
      for (int mi = 0; mi < 4; ++mi)
#pragma unroll
        for (int ni = 0; ni < 4; ++ni)
          acc[mi][ni] = __builtin_amdgcn_mfma_f32_16x16x32_bf16(
              af[mi], bfr[ni], acc[mi][ni], 0, 0, 0);
      __builtin_amdgcn_s_setprio(0);
    }
    asm volatile("s_waitcnt vmcnt(0)" ::: "memory");
    __syncthreads();
    cur = nxt;
  }

  // epilogue: C row = (l>>4)*4 + r, col = l&15 (m89-verified layout)
  const int crow = (l >> 4) * 4;
  float* Cpart = PARTIAL ? ((float*)Cv + (size_t)z * M * (size_t)N) : nullptr;
#pragma unroll
  for (int ni = 0; ni < 4; ++ni) {
    const long col = bcol + wc * 64 + ni * 16 + fr;
    const float bv = (!PARTIAL && HAS_BIAS) ? bias[col] : 0.0f;
#pragma unroll
    for (int mi = 0; mi < 4; ++mi) {
#pragma unroll
      for (int r = 0; r < 4; ++r) {
        const long row = brow + wr * 64 + mi * 16 + crow + r;
        const float v = acc[mi][ni][r] + bv;
        if (PARTIAL)
          Cpart[row * (long)N + col] = v;
        else if (OUT_BF16)
          ((unsigned short*)Cv)[row * (long)N + col] = f2bf(v);
        else
          ((float*)Cv)[row * (long)N + col] = v;
      }
    }
  }
}

// Sum S f32 partials (stride MN), emit bf16 (used for Wt).
__global__ __launch_bounds__(256) void reduce_splits_bf16(
    const float* __restrict__ part, unsigned short* __restrict__ out, int S,
    size_t MN) {
  size_t i = (size_t)blockIdx.x * 256 + threadIdx.x;  // float4 index
  const size_t n4 = MN / 4;
  const size_t stride = (size_t)gridDim.x * 256;
  for (; i < n4; i += stride) {
    float4 a = ((const float4*)part)[i];
    for (int s = 1; s < S; ++s) {
      const float4 b = ((const float4*)(part + (size_t)s * MN))[i];
      a.x += b.x; a.y += b.y; a.z += b.z; a.w += b.w;
    }
    ((ushort4*)out)[i] =
        make_ushort4(f2bf(a.x), f2bf(a.y), f2bf(a.z), f2bf(a.w));
  }
}

// ---------------------------------------------------------------------------
// LN over 4096-wide rows; fused x_q fp32 passthrough copy + bf16 LN output.
// ---------------------------------------------------------------------------
__global__ __launch_bounds__(256) void ln_q_kernel(
    const float* __restrict__ x, const float* __restrict__ w,
    const float* __restrict__ b, float* __restrict__ copy_out,
    unsigned short* __restrict__ qn) {
  const int row = blockIdx.x, t = threadIdx.x;
  const float4* xr = (const float4*)(x + (size_t)row * 4096);
  float4 v[4];
  float s = 0.f, s2 = 0.f;
#pragma unroll
  for (int j = 0; j < 4; ++j) {
    v[j] = xr[j * 256 + t];
    s += v[j].x + v[j].y + v[j].z + v[j].w;
    s2 += v[j].x * v[j].x + v[j].y * v[j].y + v[j].z * v[j].z + v[j].w * v[j].w;
  }
#pragma unroll
  for (int off = 32; off; off >>= 1) {
    s += __shfl_xor(s, off);
    s2 += __shfl_xor(s2, off);
  }
  __shared__ float red[8];
  if ((t & 63) == 0) { red[t >> 6] = s; red[4 + (t >> 6)] = s2; }
  __syncthreads();
  s = red[0] + red[1] + red[2] + red[3];
  s2 = red[4] + red[5] + red[6] + red[7];
  const float mu = s * (1.f / 4096.f);
  const float rstd = rsqrtf(s2 * (1.f / 4096.f) - mu * mu + 1e-5f);
  float4* co = (float4*)(copy_out + (size_t)row * 4096);
  unsigned short* qr = qn + (size_t)row * 4096;
#pragma unroll
  for (int j = 0; j < 4; ++j) {
    co[j * 256 + t] = v[j];
    const int c = (j * 256 + t) * 4;
    const float4 wv = *(const float4*)(w + c);
    const float4 bv = *(const float4*)(b + c);
    ushort4 o = make_ushort4(f2bf((v[j].x - mu) * rstd * wv.x + bv.x),
                             f2bf((v[j].y - mu) * rstd * wv.y + bv.y),
                             f2bf((v[j].z - mu) * rstd * wv.z + bv.z),
                             f2bf((v[j].w - mu) * rstd * wv.w + bv.w));
    *(ushort4*)(qr + c) = o;
  }
}

// LN over 1024-wide rows; two affine outputs (k and v params).
__global__ __launch_bounds__(256) void ln_kv_kernel(
    const float* __restrict__ x, const float* __restrict__ kw,
    const float* __restrict__ kb, const float* __restrict__ vw,
    const float* __restrict__ vb, unsigned short* __restrict__ kn,
    unsigned short* __restrict__ vn) {
  const int row = blockIdx.x, t = threadIdx.x;
  const float4 v = ((const float4*)(x + (size_t)row * 1024))[t];
  float s = v.x + v.y + v.z + v.w;
  float s2 = v.x * v.x + v.y * v.y + v.z * v.z + v.w * v.w;
#pragma unroll
  for (int off = 32; off; off >>= 1) {
    s += __shfl_xor(s, off);
    s2 += __shfl_xor(s2, off);
  }
  __shared__ float red[8];
  if ((t & 63) == 0) { red[t >> 6] = s; red[4 + (t >> 6)] = s2; }
  __syncthreads();
  s = red[0] + red[1] + red[2] + red[3];
  s2 = red[4] + red[5] + red[6] + red[7];
  const float mu = s * (1.f / 1024.f);
  const float rstd = rsqrtf(s2 * (1.f / 1024.f) - mu * mu + 1e-5f);
  const int c = t * 4;
  const float4 kw4 = *(const float4*)(kw + c);
  const float4 kb4 = *(const float4*)(kb + c);
  const float4 vw4 = *(const float4*)(vw + c);
  const float4 vb4 = *(const float4*)(vb + c);
  const float h0 = (v.x - mu) * rstd, h1 = (v.y - mu) * rstd;
  const float h2 = (v.z - mu) * rstd, h3 = (v.w - mu) * rstd;
  *(ushort4*)(kn + (size_t)row * 1024 + c) =
      make_ushort4(f2bf(h0 * kw4.x + kb4.x), f2bf(h1 * kw4.y + kb4.y),
                   f2bf(h2 * kw4.z + kb4.z), f2bf(h3 * kw4.w + kb4.w));
  *(ushort4*)(vn + (size_t)row * 1024 + c) =
      make_ushort4(f2bf(h0 * vw4.x + vb4.x), f2bf(h1 * vw4.y + vb4.y),
                   f2bf(h2 * vw4.z + vb4.z), f2bf(h3 * vw4.w + vb4.w));
}

// fp32 -> bf16 elementwise (n4 = count of float4 groups)
__global__ __launch_bounds__(256) void conv_bf16(
    const float* __restrict__ src, unsigned short* __restrict__ dst, int n4) {
  int i = blockIdx.x * 256 + threadIdx.x;
  const int stride = gridDim.x * 256;
  for (; i < n4; i += stride) {
    const float4 v = ((const float4*)src)[i];
    ((ushort4*)dst)[i] = make_ushort4(f2bf(v.x), f2bf(v.y), f2bf(v.z), f2bf(v.w));
  }
}

// k_w row c: bf16-convert AND qkb[c] = q_b . k_w[c,:]  (fused, one read)
__global__ __launch_bounds__(256) void conv_kw_qkb(
    const float* __restrict__ kw, const float* __restrict__ qb,
    unsigned short* __restrict__ kwb, float* __restrict__ qkb) {
  const int c = blockIdx.x, t = threadIdx.x;
  const float4* kr = (const float4*)(kw + (size_t)c * 4096);
  const float4* q4 = (const float4*)qb;
  ushort4* ko = (ushort4*)(kwb + (size_t)c * 4096);
  float s = 0.f;
#pragma unroll
  for (int j = 0; j < 4; ++j) {
    const float4 a = q4[j * 256 + t], b = kr[j * 256 + t];
    ko[j * 256 + t] = make_ushort4(f2bf(b.x), f2bf(b.y), f2bf(b.z), f2bf(b.w));
    s += a.x * b.x + a.y * b.y + a.z * b.z + a.w * b.w;
  }
#pragma unroll
  for (int off = 32; off; off >>= 1) s += __shfl_xor(s, off);
  __shared__ float red[4];
  if ((t & 63) == 0) red[t >> 6] = s;
  __syncthreads();
  if (t == 0) qkb[c] = red[0] + red[1] + red[2] + red[3];
}

// v_w [1024,4096] fp32 -> vwT [4096,1024] bf16
__global__ void transpose_conv(const float* __restrict__ src,
                               unsigned short* __restrict__ dst) {
  __shared__ float tile[32][33];
  const int n0 = blockIdx.x * 32, k0 = blockIdx.y * 32;
  const int tx = threadIdx.x, ty = threadIdx.y;
#pragma unroll
  for (int i = 0; i < 32; i += 8)
    tile[ty + i][tx] = src[(size_t)(k0 + ty + i) * 4096 + n0 + tx];
  __syncthreads();
#pragma unroll
  for (int i = 0; i < 32; i += 8)
    dst[(size_t)(n0 + ty + i) * 1024 + k0 + tx] = f2bf(tile[tx][ty + i]);
}

// Fused: qk = sum_z part_z + qkb ; logits_s = (qk . kn_s)/64 ; softmax(4) ;
// wkv = sum_s att_s * vn_s  (one block per output row m)
__global__ __launch_bounds__(256) void att_fused(
    const float* __restrict__ part, int S, size_t PMN,
    const float* __restrict__ qkb, const unsigned short* __restrict__ kn,
    const unsigned short* __restrict__ vn, unsigned short* __restrict__ wkv) {
  const int m = blockIdx.x;                 // b*576 + p
  const int b = m / 576, p = m % 576;
  const int py = p / 24, px = p % 24;
  const int t = threadIdx.x, w = t >> 6, l = t & 63;
  const int c = t * 4;
  const size_t off = (size_t)m * 1024 + c;

  float4 q = *(const float4*)(part + off);
  for (int s = 1; s < S; ++s) {
    const float4 pp = *(const float4*)(part + (size_t)s * PMN + off);
    q.x += pp.x; q.y += pp.y; q.z += pp.z; q.w += pp.w;
  }
  const float4 qb4 = *(const float4*)(qkb + c);
  q.x += qb4.x; q.y += qb4.y; q.z += qb4.z; q.w += qb4.w;

  size_t rows[4];
#pragma unroll
  for (int s = 0; s < 4; ++s)
    rows[s] = ((size_t)b * 2304 + (size_t)(py * 2 + (s >> 1)) * 48 +
               (px * 2 + (s & 1))) * 1024;

  float dot[4];
#pragma unroll
  for (int s = 0; s < 4; ++s) {
    const ushort4 k4 = *(const ushort4*)(kn + rows[s] + c);
    dot[s] = q.x * bf2f(k4.x) + q.y * bf2f(k4.y) + q.z * bf2f(k4.z) +
             q.w * bf2f(k4.w);
  }
#pragma unroll
  for (int s = 0; s < 4; ++s)
#pragma unroll
    for (int o = 32; o; o >>= 1) dot[s] += __shfl_xor(dot[s], o);

  __shared__ float red[4][4];
  if (l == 0) {
#pragma unroll
    for (int s = 0; s < 4; ++s) red[w][s] = dot[s];
  }
  __syncthreads();
  float lg[4];
#pragma unroll
  for (int s = 0; s < 4; ++s)
    lg[s] = (red[0][s] + red[1][s] + red[2][s] + red[3][s]) * 0.015625f;
  const float mx = fmaxf(fmaxf(lg[0], lg[1]), fmaxf(lg[2], lg[3]));
  float e[4];
#pragma unroll
  for (int s = 0; s < 4; ++s) e[s] = __expf(lg[s] - mx);
  const float inv = 1.f / (e[0] + e[1] + e[2] + e[3]);

  float a0 = 0.f, a1 = 0.f, a2 = 0.f, a3 = 0.f;
#pragma unroll
  for (int s = 0; s < 4; ++s) {
    const float at = e[s] * inv;
    const ushort4 v4 = *(const ushort4*)(vn + rows[s] + c);
    a0 += at * bf2f(v4.x);
    a1 += at * bf2f(v4.y);
    a2 += at * bf2f(v4.z);
    a3 += at * bf2f(v4.w);
  }
  *(ushort4*)(wkv + off) =
      make_ushort4(f2bf(a0), f2bf(a1), f2bf(a2), f2bf(a3));
}

// ---------------------------------------------------------------------------
extern "C" void kernel_launch(void* const* d_in, const int* in_sizes, int n_in,
                              void* d_out, int out_size, void* d_ws,
                              size_t ws_size, hipStream_t stream) {
  const float* x_q = (const float*)d_in[0];
  const float* x_kv = (const float*)d_in[1];
  const float* q_ln_w = (const float*)d_in[2];
  const float* q_ln_b = (const float*)d_in[3];
  const float* q_w = (const float*)d_in[4];
  const float* q_b = (const float*)d_in[5];
  const float* k_ln_w = (const float*)d_in[6];
  const float* k_ln_b = (const float*)d_in[7];
  const float* k_w = (const float*)d_in[8];
  // d_in[9] = k_b: cancels exactly in softmax -> unused
  const float* v_ln_w = (const float*)d_in[10];
  const float* v_ln_b = (const float*)d_in[11];
  const float* v_w = (const float*)d_in[12];
  const float* v_b = (const float*)d_in[13];

  char* ws = (char*)d_ws;
  unsigned short* qn = (unsigned short*)(ws);                 // 4608x4096 bf16
  unsigned short* kn = (unsigned short*)(ws + 37748736);      // 18432x1024 bf16
  unsigned short* vn = (unsigned short*)(ws + 75497472);      // 18432x1024 bf16
  unsigned short* qwb = (unsigned short*)(ws + 113246208);    // 4096x4096 bf16
  unsigned short* kwb = (unsigned short*)(ws + 146800640);    // 1024x4096 bf16
  unsigned short* Wt = (unsigned short*)(ws + 155189248);     // 1024x4096 bf16
  unsigned short* vwT = (unsigned short*)(ws + 163577856);    // 4096x1024 bf16
  float* qkbv = (float*)(ws + 190840832);                     // 1024 f32
  unsigned short* wkv = (unsigned short*)(ws + 190844928);    // 4608x1024 bf16
  float* part = (float*)(ws + 200282112);                     // split-K partials

  const size_t MN_W = (size_t)1024 * 4096;   // Wt elements
  const size_t MN_QK = (size_t)4608 * 1024;  // qk elements
  int splitW = 1, splitQK = 1;
  if (ws_size >= 200282112ull + 2 * MN_QK * 4) { splitW = 2; splitQK = 2; }
  // else: splits = 1 (partial path with S=1)

  float* out0 = (float*)d_out;                // x_q passthrough
  float* out1 = out0 + (size_t)4608 * 4096;   // feat

  ln_q_kernel<<<4608, 256, 0, stream>>>(x_q, q_ln_w, q_ln_b, out0, qn);
  ln_kv_kernel<<<18432, 256, 0, stream>>>(x_kv, k_ln_w, k_ln_b, v_ln_w, v_ln_b,
                                          kn, vn);
  conv_bf16<<<4096, 256, 0, stream>>>(q_w, qwb, 4096 * 4096 / 4);
  conv_kw_qkb<<<1024, 256, 0, stream>>>(k_w, q_b, kwb, qkbv);
  transpose_conv<<<dim3(128, 32), dim3(32, 8), 0, stream>>>(v_w, vwT);

  // Wt = k_w @ q_w^T  [1024,4096], split-K -> f32 partials -> bf16 Wt
  gemm_nt<true, false, false><<<dim3(8, 32, splitW), 256, 0, stream>>>(
      kwb, qwb, part, nullptr, 1024, 4096, 4096, 4096 / splitW);
  reduce_splits_bf16<<<2048, 256, 0, stream>>>(part, Wt, splitW, MN_W);

  // qk partials = qn @ Wt^T  [4608,1024], split-K (summed inside att_fused)
  gemm_nt<true, false, false><<<dim3(36, 8, splitQK), 256, 0, stream>>>(
      qn, Wt, part, nullptr, 4608, 1024, 4096, 4096 / splitQK);
  att_fused<<<4608, 256, 0, stream>>>(part, splitQK, MN_QK, qkbv, kn, vn, wkv);

  // out1 = wkv @ vwT^T + v_b  [4608,4096]
  gemm_nt<false, false, true><<<dim3(36, 32), 256, 0, stream>>>(
      wkv, vwT, out1, v_b, 4608, 4096, 1024, 1024);
}

// Round 6
// 551.439 us; speedup vs baseline: 1.0736x; 1.0736x over previous
//
#include <hip/hip_runtime.h>
#include <cstdint>
#include <cstddef>

// ---------------------------------------------------------------------------
// Pipeline (bf16 MFMA, fp32 accumulate):
//   ln_q:   qn = LN(x_q)*qlnw+qlnb (bf16), also copy x_q -> out0 (fp32)
//   ln_kv:  kn = LN(x_kv)*klnw+klnb, vn = LN(x_kv)*vlnw+vlnb (bf16)
//   prep:   qwb=bf16(q_w); {kwb=bf16(k_w), qkb=q_b@k_w^T} fused; vwT=bf16(v_w^T)
//   GEMM-W:  Wt partials = kwb @ qwb^T [1024,4096] split-K x2 (bf16 partials)
//   GEMM-QK: part_z = qn @ Wt^T        [4608,1024] split-K x4 (bf16 partials)
//   att_fused: qk=sum part+qkb; logits=(qk.kn_s)/64; softmax(4); wkv=sum att*vn
//   GEMM-F:  out1 = wkv @ vwT^T + v_b  [4608,4096]
// R6: REVERT R5's 2-phase dbuf (halved blocks/CU 5->2, lost TLP latency
// hiding -> regression 560->592). Back to R4's single-buffer BK=64 serial
// loop + T2 swizzle (validated). splitQK restored to 4. NEW: bf16 split-K
// partials (7x accuracy headroom) halve partial traffic (~90MB saved).
// ---------------------------------------------------------------------------

typedef __attribute__((ext_vector_type(8))) short short8;
typedef __attribute__((ext_vector_type(4))) float f32x4;

#define DEV __device__ __forceinline__

DEV unsigned short f2bf(float f) {            // f32 -> bf16 RNE
  union { float f; unsigned u; } x; x.f = f;
  unsigned r = x.u + 0x7fffu + ((x.u >> 16) & 1u);
  return (unsigned short)(r >> 16);
}
DEV float bf2f(unsigned short u) {            // bf16 -> f32 exact
  union { unsigned u; float f; } x; x.u = ((unsigned)u) << 16;
  return x.f;
}

DEV void gload16(const void* g, void* l) {    // async global->LDS, 16B/lane
  __builtin_amdgcn_global_load_lds(
      (const __attribute__((address_space(1))) unsigned int*)g,
      (__attribute__((address_space(3))) unsigned int*)l, 16, 0, 0);
}

// ---------------------------------------------------------------------------
// NT GEMM, BK=64, T2-swizzled single-buffer LDS (32KB -> ~5 blocks/CU, TLP
// does the latency hiding; m114). A[M,Kfull] bf16 rm, B[N,Kfull] bf16 rm
// (K-contig). Split-K via blockIdx.z (Kchunk each); PARTIAL writes bf16
// partial at Cv + z*M*N. Else f32 + bias. 128x128 tile, 4 waves 2x2,
// 4x4 of 16x16x32 MFMA, 2 k-steps per LDS tile. M,N%128==0, Kchunk%64==0.
// LDS layout [row][8 groups of 16B]; group g holds global group g^(row&7)
// (involution; staged via pre-swizzled SOURCE addr per rule #21, read with
// the same XOR).
// ---------------------------------------------------------------------------
template <bool PARTIAL, bool HAS_BIAS>
__global__ __launch_bounds__(256, 2) void gemm_nt(
    const unsigned short* __restrict__ A, const unsigned short* __restrict__ Bm,
    void* __restrict__ Cv, const float* __restrict__ bias, int M, int N,
    int Kfull, int Kchunk) {
  __shared__ __align__(16) unsigned short lds_a[128 * 64];
  __shared__ __align__(16) unsigned short lds_b[128 * 64];
  const int t = threadIdx.x;
  const int l = t & 63;
  const int w = t >> 6;

  int bx = blockIdx.x, by = blockIdx.y;
  {  // XCD swizzle (T1): xy-plane size is a multiple of 8 at every call site
    const int nbx = gridDim.x, nby = gridDim.y;
    const int nwg = nbx * nby;
    int flat = by * nbx + bx;
    flat = (flat & 7) * (nwg >> 3) + (flat >> 3);
    bx = flat % nbx;
    by = flat / nbx;
  }
  const long brow = (long)bx * 128;
  const long bcol = (long)by * 128;
  const int z = blockIdx.z;
  const int k0 = z * Kchunk;

  // staging: 1024 16B-slots per matrix; thread owns slots t+256j (j=0..3).
  // slot s: row = s>>3, g = s&7. source group = g ^ (row&7) (const per thread)
  const int srow0 = t >> 3;
  const int gsrc = (t & 7) ^ ((t >> 3) & 7);
  const unsigned short* aS[4];
  const unsigned short* bS[4];
  unsigned short* aD[4];
  unsigned short* bD[4];
#pragma unroll
  for (int j = 0; j < 4; ++j) {
    const long row = srow0 + 32 * j;
    aS[j] = A + (brow + row) * (long)Kfull + k0 + gsrc * 8;
    bS[j] = Bm + (bcol + row) * (long)Kfull + k0 + gsrc * 8;
    aD[j] = lds_a + (t + 256 * j) * 8;
    bD[j] = lds_b + (t + 256 * j) * 8;
  }

  const int wr = w >> 1, wc = w & 1;
  const int fr = l & 15;              // A-row / B-col within fragment
  const int xr = fr & 7;              // row-part of the group XOR
  const int gq0 = l >> 4;             // k-group within 32-k step (0..3)

  f32x4 acc[4][4] = {};

  for (int kt = 0; kt < Kchunk; kt += 64) {
    __syncthreads();                  // all prior LDS reads done
#pragma unroll
    for (int j = 0; j < 4; ++j) {
      gload16(aS[j] + kt, aD[j]);
      gload16(bS[j] + kt, bD[j]);
    }
    asm volatile("s_waitcnt vmcnt(0)" ::: "memory");
    __syncthreads();
#pragma unroll
    for (int ks = 0; ks < 2; ++ks) {
      const int gx = ((ks * 4 + gq0) ^ xr) * 8;   // swizzled 16B group offset
      short8 af[4], bfr[4];
#pragma unroll
      for (int mi = 0; mi < 4; ++mi)
        af[mi] = *(const short8*)&lds_a[(wr * 64 + mi * 16 + fr) * 64 + gx];
#pragma unroll
      for (int ni = 0; ni < 4; ++ni)
        bfr[ni] = *(const short8*)&lds_b[(wc * 64 + ni * 16 + fr) * 64 + gx];
#pragma unroll
      for (int mi = 0; mi < 4; ++mi)
#pragma unroll
        for (int ni = 0; ni < 4; ++ni)
          acc[mi][ni] = __builtin_amdgcn_mfma_f32_16x16x32_bf16(
              af[mi], bfr[ni], acc[mi][ni], 0, 0, 0);
    }
  }

  // epilogue: C row = (l>>4)*4 + r, col = l&15 (m89-verified layout)
  const int crow = (l >> 4) * 4;
  unsigned short* Cpart =
      PARTIAL ? ((unsigned short*)Cv + (size_t)z * M * (size_t)N) : nullptr;
#pragma unroll
  for (int ni = 0; ni < 4; ++ni) {
    const long col = bcol + wc * 64 + ni * 16 + fr;
    const float bv = (!PARTIAL && HAS_BIAS) ? bias[col] : 0.0f;
#pragma unroll
    for (int mi = 0; mi < 4; ++mi) {
#pragma unroll
      for (int r = 0; r < 4; ++r) {
        const long row = brow + wr * 64 + mi * 16 + crow + r;
        const float v = acc[mi][ni][r] + bv;
        if (PARTIAL)
          Cpart[row * (long)N + col] = f2bf(v);
        else
          ((float*)Cv)[row * (long)N + col] = v;
      }
    }
  }
}

// Sum S bf16 partials (stride MN elems), emit bf16 (used for Wt).
__global__ __launch_bounds__(256) void reduce_splits_bf16(
    const unsigned short* __restrict__ part, unsigned short* __restrict__ out,
    int S, size_t MN) {
  size_t i = (size_t)blockIdx.x * 256 + threadIdx.x;  // ushort4 index
  const size_t n4 = MN / 4;
  const size_t stride = (size_t)gridDim.x * 256;
  for (; i < n4; i += stride) {
    float a0 = 0.f, a1 = 0.f, a2 = 0.f, a3 = 0.f;
    for (int s = 0; s < S; ++s) {
      const ushort4 b = ((const ushort4*)(part + (size_t)s * MN))[i];
      a0 += bf2f(b.x); a1 += bf2f(b.y); a2 += bf2f(b.z); a3 += bf2f(b.w);
    }
    ((ushort4*)out)[i] = make_ushort4(f2bf(a0), f2bf(a1), f2bf(a2), f2bf(a3));
  }
}

// ---------------------------------------------------------------------------
// LN over 4096-wide rows; fused x_q fp32 passthrough copy + bf16 LN output.
// ---------------------------------------------------------------------------
__global__ __launch_bounds__(256) void ln_q_kernel(
    const float* __restrict__ x, const float* __restrict__ w,
    const float* __restrict__ b, float* __restrict__ copy_out,
    unsigned short* __restrict__ qn) {
  const int row = blockIdx.x, t = threadIdx.x;
  const float4* xr = (const float4*)(x + (size_t)row * 4096);
  float4 v[4];
  float s = 0.f, s2 = 0.f;
#pragma unroll
  for (int j = 0; j < 4; ++j) {
    v[j] = xr[j * 256 + t];
    s += v[j].x + v[j].y + v[j].z + v[j].w;
    s2 += v[j].x * v[j].x + v[j].y * v[j].y + v[j].z * v[j].z + v[j].w * v[j].w;
  }
#pragma unroll
  for (int off = 32; off; off >>= 1) {
    s += __shfl_xor(s, off);
    s2 += __shfl_xor(s2, off);
  }
  __shared__ float red[8];
  if ((t & 63) == 0) { red[t >> 6] = s; red[4 + (t >> 6)] = s2; }
  __syncthreads();
  s = red[0] + red[1] + red[2] + red[3];
  s2 = red[4] + red[5] + red[6] + red[7];
  const float mu = s * (1.f / 4096.f);
  const float rstd = rsqrtf(s2 * (1.f / 4096.f) - mu * mu + 1e-5f);
  float4* co = (float4*)(copy_out + (size_t)row * 4096);
  unsigned short* qr = qn + (size_t)row * 4096;
#pragma unroll
  for (int j = 0; j < 4; ++j) {
    co[j * 256 + t] = v[j];
    const int c = (j * 256 + t) * 4;
    const float4 wv = *(const float4*)(w + c);
    const float4 bv = *(const float4*)(b + c);
    ushort4 o = make_ushort4(f2bf((v[j].x - mu) * rstd * wv.x + bv.x),
                             f2bf((v[j].y - mu) * rstd * wv.y + bv.y),
                             f2bf((v[j].z - mu) * rstd * wv.z + bv.z),
                             f2bf((v[j].w - mu) * rstd * wv.w + bv.w));
    *(ushort4*)(qr + c) = o;
  }
}

// LN over 1024-wide rows; two affine outputs (k and v params).
__global__ __launch_bounds__(256) void ln_kv_kernel(
    const float* __restrict__ x, const float* __restrict__ kw,
    const float* __restrict__ kb, const float* __restrict__ vw,
    const float* __restrict__ vb, unsigned short* __restrict__ kn,
    unsigned short* __restrict__ vn) {
  const int row = blockIdx.x, t = threadIdx.x;
  const float4 v = ((const float4*)(x + (size_t)row * 1024))[t];
  float s = v.x + v.y + v.z + v.w;
  float s2 = v.x * v.x + v.y * v.y + v.z * v.z + v.w * v.w;
#pragma unroll
  for (int off = 32; off; off >>= 1) {
    s += __shfl_xor(s, off);
    s2 += __shfl_xor(s2, off);
  }
  __shared__ float red[8];
  if ((t & 63) == 0) { red[t >> 6] = s; red[4 + (t >> 6)] = s2; }
  __syncthreads();
  s = red[0] + red[1] + red[2] + red[3];
  s2 = red[4] + red[5] + red[6] + red[7];
  const float mu = s * (1.f / 1024.f);
  const float rstd = rsqrtf(s2 * (1.f / 1024.f) - mu * mu + 1e-5f);
  const int c = t * 4;
  const float4 kw4 = *(const float4*)(kw + c);
  const float4 kb4 = *(const float4*)(kb + c);
  const float4 vw4 = *(const float4*)(vw + c);
  const float4 vb4 = *(const float4*)(vb + c);
  const float h0 = (v.x - mu) * rstd, h1 = (v.y - mu) * rstd;
  const float h2 = (v.z - mu) * rstd, h3 = (v.w - mu) * rstd;
  *(ushort4*)(kn + (size_t)row * 1024 + c) =
      make_ushort4(f2bf(h0 * kw4.x + kb4.x), f2bf(h1 * kw4.y + kb4.y),
                   f2bf(h2 * kw4.z + kb4.z), f2bf(h3 * kw4.w + kb4.w));
  *(ushort4*)(vn + (size_t)row * 1024 + c) =
      make_ushort4(f2bf(h0 * vw4.x + vb4.x), f2bf(h1 * vw4.y + vb4.y),
                   f2bf(h2 * vw4.z + vb4.z), f2bf(h3 * vw4.w + vb4.w));
}

// fp32 -> bf16 elementwise (n4 = count of float4 groups)
__global__ __launch_bounds__(256) void conv_bf16(
    const float* __restrict__ src, unsigned short* __restrict__ dst, int n4) {
  int i = blockIdx.x * 256 + threadIdx.x;
  const int stride = gridDim.x * 256;
  for (; i < n4; i += stride) {
    const float4 v = ((const float4*)src)[i];
    ((ushort4*)dst)[i] = make_ushort4(f2bf(v.x), f2bf(v.y), f2bf(v.z), f2bf(v.w));
  }
}

// k_w row c: bf16-convert AND qkb[c] = q_b . k_w[c,:]  (fused, one read)
__global__ __launch_bounds__(256) void conv_kw_qkb(
    const float* __restrict__ kw, const float* __restrict__ qb,
    unsigned short* __restrict__ kwb, float* __restrict__ qkb) {
  const int c = blockIdx.x, t = threadIdx.x;
  const float4* kr = (const float4*)(kw + (size_t)c * 4096);
  const float4* q4 = (const float4*)qb;
  ushort4* ko = (ushort4*)(kwb + (size_t)c * 4096);
  float s = 0.f;
#pragma unroll
  for (int j = 0; j < 4; ++j) {
    const float4 a = q4[j * 256 + t], b = kr[j * 256 + t];
    ko[j * 256 + t] = make_ushort4(f2bf(b.x), f2bf(b.y), f2bf(b.z), f2bf(b.w));
    s += a.x * b.x + a.y * b.y + a.z * b.z + a.w * b.w;
  }
#pragma unroll
  for (int off = 32; off; off >>= 1) s += __shfl_xor(s, off);
  __shared__ float red[4];
  if ((t & 63) == 0) red[t >> 6] = s;
  __syncthreads();
  if (t == 0) qkb[c] = red[0] + red[1] + red[2] + red[3];
}

// v_w [1024,4096] fp32 -> vwT [4096,1024] bf16
__global__ void transpose_conv(const float* __restrict__ src,
                               unsigned short* __restrict__ dst) {
  __shared__ float tile[32][33];
  const int n0 = blockIdx.x * 32, k0 = blockIdx.y * 32;
  const int tx = threadIdx.x, ty = threadIdx.y;
#pragma unroll
  for (int i = 0; i < 32; i += 8)
    tile[ty + i][tx] = src[(size_t)(k0 + ty + i) * 4096 + n0 + tx];
  __syncthreads();
#pragma unroll
  for (int i = 0; i < 32; i += 8)
    dst[(size_t)(n0 + ty + i) * 1024 + k0 + tx] = f2bf(tile[tx][ty + i]);
}

// Fused: qk = sum_z part_z + qkb ; logits_s = (qk . kn_s)/64 ; softmax(4) ;
// wkv = sum_s att_s * vn_s  (one block per output row m). part is bf16.
__global__ __launch_bounds__(256) void att_fused(
    const unsigned short* __restrict__ part, int S, size_t PMN,
    const float* __restrict__ qkb, const unsigned short* __restrict__ kn,
    const unsigned short* __restrict__ vn, unsigned short* __restrict__ wkv) {
  const int m = blockIdx.x;                 // b*576 + p
  const int b = m / 576, p = m % 576;
  const int py = p / 24, px = p % 24;
  const int t = threadIdx.x, w = t >> 6, l = t & 63;
  const int c = t * 4;
  const size_t off = (size_t)m * 1024 + c;

  const float4 qb4 = *(const float4*)(qkb + c);
  float4 q = qb4;
  for (int s = 0; s < S; ++s) {
    const ushort4 pp = *(const ushort4*)(part + (size_t)s * PMN + off);
    q.x += bf2f(pp.x); q.y += bf2f(pp.y); q.z += bf2f(pp.z); q.w += bf2f(pp.w);
  }

  size_t rows[4];
#pragma unroll
  for (int s = 0; s < 4; ++s)
    rows[s] = ((size_t)b * 2304 + (size_t)(py * 2 + (s >> 1)) * 48 +
               (px * 2 + (s & 1))) * 1024;

  float dot[4];
#pragma unroll
  for (int s = 0; s < 4; ++s) {
    const ushort4 k4 = *(const ushort4*)(kn + rows[s] + c);
    dot[s] = q.x * bf2f(k4.x) + q.y * bf2f(k4.y) + q.z * bf2f(k4.z) +
             q.w * bf2f(k4.w);
  }
#pragma unroll
  for (int s = 0; s < 4; ++s)
#pragma unroll
    for (int o = 32; o; o >>= 1) dot[s] += __shfl_xor(dot[s], o);

  __shared__ float red[4][4];
  if (l == 0) {
#pragma unroll
    for (int s = 0; s < 4; ++s) red[w][s] = dot[s];
  }
  __syncthreads();
  float lg[4];
#pragma unroll
  for (int s = 0; s < 4; ++s)
    lg[s] = (red[0][s] + red[1][s] + red[2][s] + red[3][s]) * 0.015625f;
  const float mx = fmaxf(fmaxf(lg[0], lg[1]), fmaxf(lg[2], lg[3]));
  float e[4];
#pragma unroll
  for (int s = 0; s < 4; ++s) e[s] = __expf(lg[s] - mx);
  const float inv = 1.f / (e[0] + e[1] + e[2] + e[3]);

  float a0 = 0.f, a1 = 0.f, a2 = 0.f, a3 = 0.f;
#pragma unroll
  for (int s = 0; s < 4; ++s) {
    const float at = e[s] * inv;
    const ushort4 v4 = *(const ushort4*)(vn + rows[s] + c);
    a0 += at * bf2f(v4.x);
    a1 += at * bf2f(v4.y);
    a2 += at * bf2f(v4.z);
    a3 += at * bf2f(v4.w);
  }
  *(ushort4*)(wkv + off) =
      make_ushort4(f2bf(a0), f2bf(a1), f2bf(a2), f2bf(a3));
}

// ---------------------------------------------------------------------------
extern "C" void kernel_launch(void* const* d_in, const int* in_sizes, int n_in,
                              void* d_out, int out_size, void* d_ws,
                              size_t ws_size, hipStream_t stream) {
  const float* x_q = (const float*)d_in[0];
  const float* x_kv = (const float*)d_in[1];
  const float* q_ln_w = (const float*)d_in[2];
  const float* q_ln_b = (const float*)d_in[3];
  const float* q_w = (const float*)d_in[4];
  const float* q_b = (const float*)d_in[5];
  const float* k_ln_w = (const float*)d_in[6];
  const float* k_ln_b = (const float*)d_in[7];
  const float* k_w = (const float*)d_in[8];
  // d_in[9] = k_b: cancels exactly in softmax -> unused
  const float* v_ln_w = (const float*)d_in[10];
  const float* v_ln_b = (const float*)d_in[11];
  const float* v_w = (const float*)d_in[12];
  const float* v_b = (const float*)d_in[13];

  char* ws = (char*)d_ws;
  unsigned short* qn = (unsigned short*)(ws);                 // 4608x4096 bf16
  unsigned short* kn = (unsigned short*)(ws + 37748736);      // 18432x1024 bf16
  unsigned short* vn = (unsigned short*)(ws + 75497472);      // 18432x1024 bf16
  unsigned short* qwb = (unsigned short*)(ws + 113246208);    // 4096x4096 bf16
  unsigned short* kwb = (unsigned short*)(ws + 146800640);    // 1024x4096 bf16
  unsigned short* Wt = (unsigned short*)(ws + 155189248);     // 1024x4096 bf16
  unsigned short* vwT = (unsigned short*)(ws + 163577856);    // 4096x1024 bf16
  float* qkbv = (float*)(ws + 190840832);                     // 1024 f32
  unsigned short* wkv = (unsigned short*)(ws + 190844928);    // 4608x1024 bf16
  unsigned short* part = (unsigned short*)(ws + 200282112);   // bf16 partials

  const size_t MN_W = (size_t)1024 * 4096;   // Wt elements
  const size_t MN_QK = (size_t)4608 * 1024;  // qk elements
  int splitW = 1, splitQK = 1;
  if (ws_size >= 200282112ull + 4 * MN_QK * 2) { splitW = 2; splitQK = 4; }
  else if (ws_size >= 200282112ull + 2 * MN_QK * 2) { splitW = 2; splitQK = 2; }
  // else: splits = 1 (partial path with S=1)

  float* out0 = (float*)d_out;                // x_q passthrough
  float* out1 = out0 + (size_t)4608 * 4096;   // feat

  ln_q_kernel<<<4608, 256, 0, stream>>>(x_q, q_ln_w, q_ln_b, out0, qn);
  ln_kv_kernel<<<18432, 256, 0, stream>>>(x_kv, k_ln_w, k_ln_b, v_ln_w, v_ln_b,
                                          kn, vn);
  conv_bf16<<<4096, 256, 0, stream>>>(q_w, qwb, 4096 * 4096 / 4);
  conv_kw_qkb<<<1024, 256, 0, stream>>>(k_w, q_b, kwb, qkbv);
  transpose_conv<<<dim3(128, 32), dim3(32, 8), 0, stream>>>(v_w, vwT);

  // Wt = k_w @ q_w^T  [1024,4096], split-K -> bf16 partials -> bf16 Wt
  gemm_nt<true, false><<<dim3(8, 32, splitW), 256, 0, stream>>>(
      kwb, qwb, part, nullptr, 1024, 4096, 4096, 4096 / splitW);
  reduce_splits_bf16<<<2048, 256, 0, stream>>>(part, Wt, splitW, MN_W);

  // qk partials = qn @ Wt^T  [4608,1024], split-K (summed inside att_fused)
  gemm_nt<true, false><<<dim3(36, 8, splitQK), 256, 0, stream>>>(
      qn, Wt, part, nullptr, 4608, 1024, 4096, 4096 / splitQK);
  att_fused<<<4608, 256, 0, stream>>>(part, splitQK, MN_QK, qkbv, kn, vn, wkv);

  // out1 = wkv @ vwT^T + v_b  [4608,4096]
  gemm_nt<false, true><<<dim3(36, 32), 256, 0, stream>>>(
      wkv, vwT, out1, v_b, 4608, 4096, 1024, 1024);
}